// Round 2
// baseline (1489.407 us; speedup 1.0000x reference)
//
#include <hip/hip_runtime.h>
#include <hip/hip_bf16.h>

#define BB 8
#define TT 168
#define NN 425
#define EE 2048
#define II 128
#define HH 256
#define F1 10
#define F2 32
#define BT (BB*TT)       // 1344
#define K2 (NN*F2)       // 13600
#define N2 (2*NN)        // 850

// LSTM register/LDS split of Whh (fp16): per thread 4 rows x 104 half2 in
// VGPRs (416 regs), 4 rows x 24 half2 in LDS (96 KB total).
#define RJ 104           // half2 per row in registers (k2 in [0,104))
#define LC 6             // LDS chunks of 4 half2 per row (k2 in [104,128))
#define WLDSN (4*LC*256*4)   // 24576 h2 elements

typedef _Float16 h2 __attribute__((ext_vector_type(2)));
typedef _Float16 h8 __attribute__((ext_vector_type(8)));

__device__ __forceinline__ float relu_(float x){ return fmaxf(x, 0.f); }
__device__ __forceinline__ float sigmoid_(float x){ return 1.f/(1.f + expf(-x)); }
__device__ __forceinline__ float bf2f_(unsigned short u){ return __uint_as_float(((unsigned)u) << 16); }
__device__ __forceinline__ float dot2_(h2 a, h2 b, float c){
#if __has_builtin(__builtin_amdgcn_fdot2)
    return __builtin_amdgcn_fdot2(a, b, c, false);
#else
    return c + (float)a[0]*(float)b[0] + (float)a[1]*(float)b[1];
#endif
}

// ---------------- GCN: two layers fused, one block per (b,t) graph ----------
__global__ __launch_bounds__(256) void gcn_kernel(
    const float* __restrict__ nf, const int* __restrict__ esrc,
    const int* __restrict__ edst, const float* __restrict__ ew,
    const float* __restrict__ Wg1, const float* __restrict__ bg1,
    const float* __restrict__ Wg2, const float* __restrict__ bg2,
    __hip_bfloat16* __restrict__ x2g)
{
    __shared__ float xs[NN];
    __shared__ float dinv[NN];
    __shared__ float agg1[NN];
    __shared__ float nrm[EE];
    __shared__ float x1[NN*F1];
    __shared__ float agg2[NN*F1];
    __shared__ float wg1s[F1], bg1s[F1], wg2s[F1*F2], bg2s[F2];

    const int bt = blockIdx.x, tid = threadIdx.x;
    const long eb = (long)bt * EE;

    for (int v = tid; v < NN; v += 256) {
        xs[v] = nf[(long)bt*NN + v];
        dinv[v] = 1.0f;
        agg1[v] = 0.f;
    }
    for (int i = tid; i < NN*F1; i += 256) agg2[i] = 0.f;
    if (tid < F1) { wg1s[tid] = Wg1[tid]; bg1s[tid] = bg1[tid]; }
    if (tid < F2) bg2s[tid] = bg2[tid];
    for (int i = tid; i < F1*F2; i += 256) wg2s[i] = Wg2[i];
    __syncthreads();

    for (int e = tid; e < EE; e += 256)
        atomicAdd(&dinv[edst[eb+e]], ew[eb+e]);
    __syncthreads();
    for (int v = tid; v < NN; v += 256) {
        float dg = dinv[v];
        dinv[v] = dg > 0.f ? 1.0f / sqrtf(fmaxf(dg, 1e-12f)) : 0.f;
    }
    __syncthreads();

    for (int e = tid; e < EE; e += 256) {
        int s = esrc[eb+e], d = edst[eb+e];
        float nm = dinv[s] * ew[eb+e] * dinv[d];
        nrm[e] = nm;
        atomicAdd(&agg1[d], nm * xs[s]);
    }
    __syncthreads();
    for (int v = tid; v < NN; v += 256) agg1[v] += dinv[v]*dinv[v]*xs[v];
    __syncthreads();
    for (int i = tid; i < NN*F1; i += 256) {
        int v = i / F1, f = i - v*F1;
        x1[i] = relu_(agg1[v] * wg1s[f] + bg1s[f]);
    }
    __syncthreads();

    for (int e = tid; e < EE; e += 256) {
        int s = esrc[eb+e], d = edst[eb+e];
        float nm = nrm[e];
        #pragma unroll
        for (int f = 0; f < F1; ++f)
            atomicAdd(&agg2[d*F1+f], nm * x1[s*F1+f]);
    }
    __syncthreads();
    for (int i = tid; i < NN*F1; i += 256) {
        int v = i / F1;
        agg2[i] += dinv[v]*dinv[v]*x1[i];
    }
    __syncthreads();

    for (int i = tid; i < NN*F2; i += 256) {
        int v = i >> 5, k = i & 31;
        float o = bg2s[k];
        #pragma unroll
        for (int f = 0; f < F1; ++f) o += agg2[v*F1+f] * wg2s[f*F2+k];
        x2g[(long)bt*K2 + i] = __float2bfloat16(relu_(o));
    }
}

// ---------------- split-K fp32 GEMM: g_pre += x2 @ Wgfc ---------------------
#define GMT 64
#define GKS 16
#define GKC 800
__global__ __launch_bounds__(256) void gemm_kernel(
    const __hip_bfloat16* __restrict__ A, const float* __restrict__ Bw,
    float* __restrict__ C)
{
    __shared__ __align__(16) float As[GKS][GMT];
    __shared__ __align__(16) float Bs[GKS][II];
    const int tid = threadIdx.x;
    const int row0 = blockIdx.x * GMT;
    const int kbase = blockIdx.y * GKC;

    const int lr = tid >> 2, lk0 = (tid & 3) * 4;
    const int bk = tid >> 4, bc = (tid & 15) * 8;
    const int r0 = (tid >> 5) << 3;
    const int c0 = (tid & 31) << 2;

    float acc[8][4];
    #pragma unroll
    for (int x = 0; x < 8; ++x)
        #pragma unroll
        for (int y = 0; y < 4; ++y) acc[x][y] = 0.f;

    for (int ks = 0; ks < GKC; ks += GKS) {
        const ushort* ap = (const ushort*)A + (long)(row0+lr)*K2 + kbase + ks + lk0;
        ushort4 av = *(const ushort4*)ap;
        As[lk0+0][lr] = bf2f_(av.x);
        As[lk0+1][lr] = bf2f_(av.y);
        As[lk0+2][lr] = bf2f_(av.z);
        As[lk0+3][lr] = bf2f_(av.w);
        const float* bp = Bw + (long)(kbase+ks+bk)*II + bc;
        *(float4*)&Bs[bk][bc]   = *(const float4*)bp;
        *(float4*)&Bs[bk][bc+4] = *(const float4*)(bp+4);
        __syncthreads();
        #pragma unroll
        for (int kk = 0; kk < GKS; ++kk) {
            float4 a0 = *(const float4*)&As[kk][r0];
            float4 a1 = *(const float4*)&As[kk][r0+4];
            float4 bv = *(const float4*)&Bs[kk][c0];
            float a[8] = {a0.x,a0.y,a0.z,a0.w,a1.x,a1.y,a1.z,a1.w};
            float b[4] = {bv.x,bv.y,bv.z,bv.w};
            #pragma unroll
            for (int x = 0; x < 8; ++x)
                #pragma unroll
                for (int y = 0; y < 4; ++y) acc[x][y] += a[x]*b[y];
        }
        __syncthreads();
    }
    #pragma unroll
    for (int x = 0; x < 8; ++x)
        #pragma unroll
        for (int y = 0; y < 4; ++y)
            atomicAdd(&C[(long)(row0+r0+x)*II + c0 + y], acc[x][y]);
}

// ---------------- infect & temp MLP branches (16 rows per block) ------------
__global__ __launch_bounds__(256) void branches_kernel(
    const float* __restrict__ infect, const float* __restrict__ temp,
    const float* __restrict__ Wi1, const float* __restrict__ bi1,
    const float* __restrict__ Wi2, const float* __restrict__ bi2,
    const float* __restrict__ Wi3, const float* __restrict__ bi3,
    const float* __restrict__ Wi4, const float* __restrict__ bi4,
    const float* __restrict__ Wt1, const float* __restrict__ bt1,
    const float* __restrict__ Wt2, const float* __restrict__ bt2,
    float* __restrict__ infout, float* __restrict__ tpout)
{
    __shared__ float inA[16*25], inT[16*13];
    __shared__ float bufA[16*II], bufB[16*II];
    const int r0 = blockIdx.x * 16, tid = threadIdx.x;

    for (int i = tid; i < 16*25; i += 256) { int r=i/25,k=i-r*25; inA[i] = infect[(long)(r0+r)*25+k]; }
    for (int i = tid; i < 16*13; i += 256) { int r=i/13,k=i-r*13; inT[i] = temp[(long)(r0+r)*13+k]; }
    __syncthreads();
    for (int i = tid; i < 16*II; i += 256) { int r=i>>7,u=i&127; float o=bi1[u];
        for (int k=0;k<25;++k) o += inA[r*25+k]*Wi1[k*II+u];
        bufA[i]=relu_(o); }
    __syncthreads();
    for (int i = tid; i < 16*II; i += 256) { int r=i>>7,u=i&127; float o=bi2[u];
        for (int k=0;k<II;++k) o += bufA[r*II+k]*Wi2[k*II+u];
        bufB[i]=relu_(o); }
    __syncthreads();
    for (int i = tid; i < 16*64; i += 256) { int r=i>>6,u=i&63; float o=bi3[u];
        for (int k=0;k<II;++k) o += bufB[r*II+k]*Wi3[k*64+u];
        bufA[r*64+u]=relu_(o); }
    __syncthreads();
    for (int i = tid; i < 16*II; i += 256) { int r=i>>7,u=i&127; float o=bi4[u];
        for (int k=0;k<64;++k) o += bufA[r*64+k]*Wi4[k*II+u];
        infout[(long)(r0+r)*II+u]=relu_(o); }
    for (int i = tid; i < 16*64; i += 256) { int r=i>>6,u=i&63; float o=bt1[u];
        for (int k=0;k<13;++k) o += inT[r*13+k]*Wt1[k*64+u];
        bufB[r*64+u]=relu_(o); }
    __syncthreads();
    for (int i = tid; i < 16*II; i += 256) { int r=i>>7,u=i&127; float o=bt2[u];
        for (int k=0;k<64;++k) o += bufB[r*64+k]*Wt2[k*II+u];
        tpout[(long)(r0+r)*II+u]=relu_(o); }
}

// ---------------- li = relu(cat@Wcat+bcat); xg = li@Wih^T + bih + bhh -------
__global__ __launch_bounds__(256) void li_xg_kernel(
    const float* __restrict__ g_pre, const float* __restrict__ bgfc,
    const float* __restrict__ infb, const float* __restrict__ tpb,
    const float* __restrict__ Wcat, const float* __restrict__ bcat,
    const float* __restrict__ Wih, const float* __restrict__ bih,
    const float* __restrict__ bhh, float* __restrict__ xg)
{
    __shared__ float cat[16*384];
    __shared__ __align__(16) float li[16*II];
    const int r0 = blockIdx.x * 16, tid = threadIdx.x;

    for (int i = tid; i < 16*II; i += 256) {
        int r = i>>7, u = i&127;
        cat[r*384 + u]       = relu_(g_pre[(long)(r0+r)*II+u] + bgfc[u]);
        cat[r*384 + 128 + u] = infb[(long)(r0+r)*II+u];
        cat[r*384 + 256 + u] = tpb[(long)(r0+r)*II+u];
    }
    __syncthreads();
    {
        int u = tid & 127, rh = tid >> 7;
        float acc[8];
        #pragma unroll
        for (int x = 0; x < 8; ++x) acc[x] = bcat[u];
        for (int k = 0; k < 384; ++k) {
            float w = Wcat[k*II+u];
            #pragma unroll
            for (int x = 0; x < 8; ++x) acc[x] += cat[(rh*8+x)*384 + k] * w;
        }
        #pragma unroll
        for (int x = 0; x < 8; ++x) li[(rh*8+x)*II + u] = relu_(acc[x]);
    }
    __syncthreads();
    for (int jj = 0; jj < 4; ++jj) {
        int j = tid + jj*256;
        float bb = bih[j] + bhh[j];
        float acc[16];
        #pragma unroll
        for (int r = 0; r < 16; ++r) acc[r] = bb;
        for (int k4 = 0; k4 < 32; ++k4) {
            float4 wv = *(const float4*)&Wih[(long)j*II + k4*4];
            #pragma unroll
            for (int r = 0; r < 16; ++r) {
                float4 lv = *(const float4*)&li[r*II + k4*4];
                acc[r] += wv.x*lv.x + wv.y*lv.y + wv.z*lv.z + wv.w*lv.w;
            }
        }
        #pragma unroll
        for (int r = 0; r < 16; ++r) xg[(long)(r0+r)*1024 + j] = acc[r];
    }
}

// ---------------- pack Whh fp32 -> fp16 register/LDS layouts ----------------
// wreg_pack: [u(256)][r(4)][j(104)] h2, k2 = j           (106496 elements)
// wlds_pack: [r(4)][c(6)][u(256)][q(4)] h2, k2 = 104+4c+q (24576 elements)
__global__ __launch_bounds__(256) void pack_whh_kernel(
    const float* __restrict__ Whh, h2* __restrict__ wreg_pack,
    h2* __restrict__ wlds_pack)
{
    int i = blockIdx.x*256 + threadIdx.x;
    if (i < 256*4*RJ) {
        int u = i / (4*RJ), rem = i % (4*RJ), r = rem / RJ, j = rem % RJ;
        int row = r*256 + u;
        h2 v; v[0] = (_Float16)Whh[(long)row*HH + 2*j];
        v[1] = (_Float16)Whh[(long)row*HH + 2*j + 1];
        wreg_pack[i] = v;
    } else {
        int L = i - 256*4*RJ;
        if (L < WLDSN) {
            int q = L & 3, u = (L >> 2) & 255, rc = L >> 10;
            int cc = rc % LC, r = rc / LC;
            int k2 = RJ + cc*4 + q, row = r*256 + u;
            h2 v; v[0] = (_Float16)Whh[(long)row*HH + 2*k2];
            v[1] = (_Float16)Whh[(long)row*HH + 2*k2 + 1];
            wlds_pack[L] = v;
        }
    }
}

// ---------------- LSTM: one block per batch, weights resident ---------------
// thread u owns unit u: rows {u, 256+u, 512+u, 768+u} (gates i,f,g,o), full K.
__global__ __launch_bounds__(256, 1) void lstm_kernel(
    const float* __restrict__ xg, const h2* __restrict__ wreg_pack,
    const h2* __restrict__ wlds_pack, const float* __restrict__ h0,
    const float* __restrict__ c0, float* __restrict__ hbuf)
{
    const int u = threadIdx.x;
    const int b = blockIdx.x;

    __shared__ __align__(16) _Float16 harr[2][HH];
    __shared__ __align__(16) h2 wlds[WLDSN];

    for (int i = u; i < WLDSN; i += 256) wlds[i] = wlds_pack[i];

    h8 wreg[4*26];                       // 416 VGPRs, static-indexed only
    {
        const h8* wp = (const h8*)wreg_pack + (size_t)u * (RJ);   // 104 h8? no:
        // per-thread data = 4*RJ h2 = 416 h2 = 104 h8 chunks, contiguous.
        #pragma unroll
        for (int m = 0; m < 104; ++m) wreg[m] = wp[m];
    }

    float c = c0[b*HH + u];
    harr[0][u] = (_Float16)h0[b*HH + u];
    __syncthreads();

    const float* xgb = xg + (size_t)b*TT*1024;
    float h_last = 0.f;

    #pragma unroll 1
    for (int t = 0; t < TT; ++t) {
        const int cb = t & 1;
        float xi = xgb[t*1024 + u];
        float xf = xgb[t*1024 + 256 + u];
        float xG = xgb[t*1024 + 512 + u];
        float xo = xgb[t*1024 + 768 + u];

        const h8* hp = (const h8*)&harr[cb][0];
        float a0[4] = {0.f,0.f,0.f,0.f};
        float a1[4] = {0.f,0.f,0.f,0.f};

        #pragma unroll
        for (int jj = 0; jj < 26; ++jj) {
            h8 hv = hp[jj];
            h2 hq0 = __builtin_shufflevector(hv, hv, 0, 1);
            h2 hq1 = __builtin_shufflevector(hv, hv, 2, 3);
            h2 hq2 = __builtin_shufflevector(hv, hv, 4, 5);
            h2 hq3 = __builtin_shufflevector(hv, hv, 6, 7);
            #pragma unroll
            for (int r = 0; r < 4; ++r) {
                h8 wv = wreg[r*26 + jj];
                h2 w0 = __builtin_shufflevector(wv, wv, 0, 1);
                h2 w1 = __builtin_shufflevector(wv, wv, 2, 3);
                h2 w2 = __builtin_shufflevector(wv, wv, 4, 5);
                h2 w3 = __builtin_shufflevector(wv, wv, 6, 7);
                a0[r] = dot2_(w0, hq0, a0[r]);
                a1[r] = dot2_(w1, hq1, a1[r]);
                a0[r] = dot2_(w2, hq2, a0[r]);
                a1[r] = dot2_(w3, hq3, a1[r]);
            }
        }
        #pragma unroll
        for (int cc = 0; cc < LC; ++cc) {
            h8 hv = hp[26 + cc];
            h2 hq0 = __builtin_shufflevector(hv, hv, 0, 1);
            h2 hq1 = __builtin_shufflevector(hv, hv, 2, 3);
            h2 hq2 = __builtin_shufflevector(hv, hv, 4, 5);
            h2 hq3 = __builtin_shufflevector(hv, hv, 6, 7);
            #pragma unroll
            for (int r = 0; r < 4; ++r) {
                h8 wv = *((const h8*)wlds + ((r*LC + cc)*256 + u));
                h2 w0 = __builtin_shufflevector(wv, wv, 0, 1);
                h2 w1 = __builtin_shufflevector(wv, wv, 2, 3);
                h2 w2 = __builtin_shufflevector(wv, wv, 4, 5);
                h2 w3 = __builtin_shufflevector(wv, wv, 6, 7);
                a0[r] = dot2_(w0, hq0, a0[r]);
                a1[r] = dot2_(w1, hq1, a1[r]);
                a0[r] = dot2_(w2, hq2, a0[r]);
                a1[r] = dot2_(w3, hq3, a1[r]);
            }
        }

        float gi = a0[0] + a1[0] + xi;
        float gf = a0[1] + a1[1] + xf;
        float gg = a0[2] + a1[2] + xG;
        float go = a0[3] + a1[3] + xo;
        c = sigmoid_(gf)*c + sigmoid_(gi)*tanhf(gg);
        float h = sigmoid_(go)*tanhf(c);
        harr[cb^1][u] = (_Float16)h;
        h_last = h;
        __syncthreads();
    }
    hbuf[b*HH + u] = h_last;
}

// ---------------- final FC: out = relu(relu(h_T) @ Wfc + bfc) ---------------
__global__ __launch_bounds__(256) void final_fc_kernel(
    const float* __restrict__ hbuf, const float* __restrict__ Wfc,
    const float* __restrict__ bfc, float* __restrict__ out)
{
    int idx = blockIdx.x*256 + threadIdx.x;
    if (idx >= BB*N2) return;
    int b = idx / N2, j = idx - b*N2;
    const float* h = hbuf + b*HH;
    float o = bfc[j];
    for (int k = 0; k < HH; ++k) o += fmaxf(h[k], 0.f) * Wfc[(long)k*N2 + j];
    out[idx] = relu_(o);
}

extern "C" void kernel_launch(void* const* d_in, const int* in_sizes, int n_in,
                              void* d_out, int out_size, void* d_ws, size_t ws_size,
                              hipStream_t stream) {
    const float* nf     = (const float*)d_in[0];
    const int*   esrc   = (const int*)d_in[1];
    const int*   edst   = (const int*)d_in[2];
    const float* ew     = (const float*)d_in[3];
    const float* infect = (const float*)d_in[4];
    const float* temp   = (const float*)d_in[5];
    const float* h0     = (const float*)d_in[6];
    const float* c0     = (const float*)d_in[7];
    const float* Wg1    = (const float*)d_in[8];
    const float* bg1    = (const float*)d_in[9];
    const float* Wg2    = (const float*)d_in[10];
    const float* bg2    = (const float*)d_in[11];
    const float* Wgfc   = (const float*)d_in[12];
    const float* bgfc   = (const float*)d_in[13];
    const float* Wi1    = (const float*)d_in[14];
    const float* bi1    = (const float*)d_in[15];
    const float* Wi2    = (const float*)d_in[16];
    const float* bi2    = (const float*)d_in[17];
    const float* Wi3    = (const float*)d_in[18];
    const float* bi3    = (const float*)d_in[19];
    const float* Wi4    = (const float*)d_in[20];
    const float* bi4    = (const float*)d_in[21];
    const float* Wt1    = (const float*)d_in[22];
    const float* bt1    = (const float*)d_in[23];
    const float* Wt2    = (const float*)d_in[24];
    const float* bt2    = (const float*)d_in[25];
    const float* Wcat   = (const float*)d_in[26];
    const float* bcat   = (const float*)d_in[27];
    const float* Wih    = (const float*)d_in[28];
    const float* Whh    = (const float*)d_in[29];
    const float* bih    = (const float*)d_in[30];
    const float* bhh    = (const float*)d_in[31];
    const float* Wfc    = (const float*)d_in[32];
    const float* bfc    = (const float*)d_in[33];

    char* ws = (char*)d_ws;
    size_t off = 0;
    __hip_bfloat16* x2g = (__hip_bfloat16*)(ws + off); off += (size_t)BT*K2*2;
    float* g_pre = (float*)(ws + off); off += (size_t)BT*II*4;
    float* infb  = (float*)(ws + off); off += (size_t)BT*II*4;
    float* tpb   = (float*)(ws + off); off += (size_t)BT*II*4;
    float* xg    = (float*)(ws + off); off += (size_t)BT*1024*4;
    float* hbuf  = (float*)(ws + off); off += (size_t)BB*HH*4;
    h2* wreg_pack = (h2*)(ws + off); off += (size_t)256*4*RJ*4;
    h2* wlds_pack = (h2*)(ws + off); off += (size_t)WLDSN*4;

    hipMemsetAsync(g_pre, 0, (size_t)BT*II*4, stream);

    pack_whh_kernel<<<512, 256, 0, stream>>>(Whh, wreg_pack, wlds_pack);
    gcn_kernel<<<BT, 256, 0, stream>>>(nf, esrc, edst, ew, Wg1, bg1, Wg2, bg2, x2g);
    branches_kernel<<<BT/16, 256, 0, stream>>>(infect, temp, Wi1, bi1, Wi2, bi2,
                                               Wi3, bi3, Wi4, bi4, Wt1, bt1, Wt2, bt2,
                                               infb, tpb);
    gemm_kernel<<<dim3(BT/GMT, K2/GKC), 256, 0, stream>>>(x2g, Wgfc, g_pre);
    li_xg_kernel<<<BT/16, 256, 0, stream>>>(g_pre, bgfc, infb, tpb, Wcat, bcat,
                                            Wih, bih, bhh, xg);
    lstm_kernel<<<BB, 256, 0, stream>>>(xg, wreg_pack, wlds_pack, h0, c0, hbuf);
    final_fc_kernel<<<(BB*N2 + 255)/256, 256, 0, stream>>>(hbuf, Wfc, bfc, (float*)d_out);
}

// Round 3
// 778.991 us; speedup vs baseline: 1.9120x; 1.9120x over previous
//
#include <hip/hip_runtime.h>
#include <hip/hip_bf16.h>

#define BB 8
#define TT 168
#define NN 425
#define EE 2048
#define II 128
#define HH 256
#define F1 10
#define F2 32
#define BT (BB*TT)       // 1344
#define K2 (NN*F2)       // 13600
#define N2 (2*NN)        // 850

// LSTM: 512 threads/block, thread owns 2 rows of Whh (fp16).
// Per row: 96 h2 in VGPRs (2x96=192 regs), 32 h2 in LDS (128 KB/block).
#define RJ2 96            // h2 per row in registers  (k2 in [0,96))
#define RJ8 24            // = RJ2/4, h8 chunks per row in registers
#define LC8 8             // h8 chunks per row in LDS (k2 in [96,128))
#define WREG_H2 (512*2*RJ2)        // 98304 h2
#define WLDS_H8 (2*LC8*512)        // 8192 h8 = 128 KB

typedef _Float16 h2 __attribute__((ext_vector_type(2)));
typedef _Float16 h8 __attribute__((ext_vector_type(8)));

__device__ __forceinline__ float relu_(float x){ return fmaxf(x, 0.f); }
__device__ __forceinline__ float sigmoid_(float x){ return 1.f/(1.f + expf(-x)); }
__device__ __forceinline__ float bf2f_(unsigned short u){ return __uint_as_float(((unsigned)u) << 16); }
__device__ __forceinline__ float dot2_(h2 a, h2 b, float c){
#if __has_builtin(__builtin_amdgcn_fdot2)
    return __builtin_amdgcn_fdot2(a, b, c, false);
#else
    return c + (float)a[0]*(float)b[0] + (float)a[1]*(float)b[1];
#endif
}

// ---------------- GCN: two layers fused, one block per (b,t) graph ----------
__global__ __launch_bounds__(256) void gcn_kernel(
    const float* __restrict__ nf, const int* __restrict__ esrc,
    const int* __restrict__ edst, const float* __restrict__ ew,
    const float* __restrict__ Wg1, const float* __restrict__ bg1,
    const float* __restrict__ Wg2, const float* __restrict__ bg2,
    __hip_bfloat16* __restrict__ x2g)
{
    __shared__ float xs[NN];
    __shared__ float dinv[NN];
    __shared__ float agg1[NN];
    __shared__ float nrm[EE];
    __shared__ float x1[NN*F1];
    __shared__ float agg2[NN*F1];
    __shared__ float wg1s[F1], bg1s[F1], wg2s[F1*F2], bg2s[F2];

    const int bt = blockIdx.x, tid = threadIdx.x;
    const long eb = (long)bt * EE;

    for (int v = tid; v < NN; v += 256) {
        xs[v] = nf[(long)bt*NN + v];
        dinv[v] = 1.0f;
        agg1[v] = 0.f;
    }
    for (int i = tid; i < NN*F1; i += 256) agg2[i] = 0.f;
    if (tid < F1) { wg1s[tid] = Wg1[tid]; bg1s[tid] = bg1[tid]; }
    if (tid < F2) bg2s[tid] = bg2[tid];
    for (int i = tid; i < F1*F2; i += 256) wg2s[i] = Wg2[i];
    __syncthreads();

    for (int e = tid; e < EE; e += 256)
        atomicAdd(&dinv[edst[eb+e]], ew[eb+e]);
    __syncthreads();
    for (int v = tid; v < NN; v += 256) {
        float dg = dinv[v];
        dinv[v] = dg > 0.f ? 1.0f / sqrtf(fmaxf(dg, 1e-12f)) : 0.f;
    }
    __syncthreads();

    for (int e = tid; e < EE; e += 256) {
        int s = esrc[eb+e], d = edst[eb+e];
        float nm = dinv[s] * ew[eb+e] * dinv[d];
        nrm[e] = nm;
        atomicAdd(&agg1[d], nm * xs[s]);
    }
    __syncthreads();
    for (int v = tid; v < NN; v += 256) agg1[v] += dinv[v]*dinv[v]*xs[v];
    __syncthreads();
    for (int i = tid; i < NN*F1; i += 256) {
        int v = i / F1, f = i - v*F1;
        x1[i] = relu_(agg1[v] * wg1s[f] + bg1s[f]);
    }
    __syncthreads();

    for (int e = tid; e < EE; e += 256) {
        int s = esrc[eb+e], d = edst[eb+e];
        float nm = nrm[e];
        #pragma unroll
        for (int f = 0; f < F1; ++f)
            atomicAdd(&agg2[d*F1+f], nm * x1[s*F1+f]);
    }
    __syncthreads();
    for (int i = tid; i < NN*F1; i += 256) {
        int v = i / F1;
        agg2[i] += dinv[v]*dinv[v]*x1[i];
    }
    __syncthreads();

    for (int i = tid; i < NN*F2; i += 256) {
        int v = i >> 5, k = i & 31;
        float o = bg2s[k];
        #pragma unroll
        for (int f = 0; f < F1; ++f) o += agg2[v*F1+f] * wg2s[f*F2+k];
        x2g[(long)bt*K2 + i] = __float2bfloat16(relu_(o));
    }
}

// ---------------- split-K fp32 GEMM: g_pre += x2 @ Wgfc ---------------------
#define GMT 64
#define GKS 16
#define GKC 800
__global__ __launch_bounds__(256) void gemm_kernel(
    const __hip_bfloat16* __restrict__ A, const float* __restrict__ Bw,
    float* __restrict__ C)
{
    __shared__ __align__(16) float As[GKS][GMT];
    __shared__ __align__(16) float Bs[GKS][II];
    const int tid = threadIdx.x;
    const int row0 = blockIdx.x * GMT;
    const int kbase = blockIdx.y * GKC;

    const int lr = tid >> 2, lk0 = (tid & 3) * 4;
    const int bk = tid >> 4, bc = (tid & 15) * 8;
    const int r0 = (tid >> 5) << 3;
    const int c0 = (tid & 31) << 2;

    float acc[8][4];
    #pragma unroll
    for (int x = 0; x < 8; ++x)
        #pragma unroll
        for (int y = 0; y < 4; ++y) acc[x][y] = 0.f;

    for (int ks = 0; ks < GKC; ks += GKS) {
        const ushort* ap = (const ushort*)A + (long)(row0+lr)*K2 + kbase + ks + lk0;
        ushort4 av = *(const ushort4*)ap;
        As[lk0+0][lr] = bf2f_(av.x);
        As[lk0+1][lr] = bf2f_(av.y);
        As[lk0+2][lr] = bf2f_(av.z);
        As[lk0+3][lr] = bf2f_(av.w);
        const float* bp = Bw + (long)(kbase+ks+bk)*II + bc;
        *(float4*)&Bs[bk][bc]   = *(const float4*)bp;
        *(float4*)&Bs[bk][bc+4] = *(const float4*)(bp+4);
        __syncthreads();
        #pragma unroll
        for (int kk = 0; kk < GKS; ++kk) {
            float4 a0 = *(const float4*)&As[kk][r0];
            float4 a1 = *(const float4*)&As[kk][r0+4];
            float4 bv = *(const float4*)&Bs[kk][c0];
            float a[8] = {a0.x,a0.y,a0.z,a0.w,a1.x,a1.y,a1.z,a1.w};
            float b[4] = {bv.x,bv.y,bv.z,bv.w};
            #pragma unroll
            for (int x = 0; x < 8; ++x)
                #pragma unroll
                for (int y = 0; y < 4; ++y) acc[x][y] += a[x]*b[y];
        }
        __syncthreads();
    }
    #pragma unroll
    for (int x = 0; x < 8; ++x)
        #pragma unroll
        for (int y = 0; y < 4; ++y)
            atomicAdd(&C[(long)(row0+r0+x)*II + c0 + y], acc[x][y]);
}

// ---------------- infect & temp MLP branches (16 rows per block) ------------
__global__ __launch_bounds__(256) void branches_kernel(
    const float* __restrict__ infect, const float* __restrict__ temp,
    const float* __restrict__ Wi1, const float* __restrict__ bi1,
    const float* __restrict__ Wi2, const float* __restrict__ bi2,
    const float* __restrict__ Wi3, const float* __restrict__ bi3,
    const float* __restrict__ Wi4, const float* __restrict__ bi4,
    const float* __restrict__ Wt1, const float* __restrict__ bt1,
    const float* __restrict__ Wt2, const float* __restrict__ bt2,
    float* __restrict__ infout, float* __restrict__ tpout)
{
    __shared__ float inA[16*25], inT[16*13];
    __shared__ float bufA[16*II], bufB[16*II];
    const int r0 = blockIdx.x * 16, tid = threadIdx.x;

    for (int i = tid; i < 16*25; i += 256) { int r=i/25,k=i-r*25; inA[i] = infect[(long)(r0+r)*25+k]; }
    for (int i = tid; i < 16*13; i += 256) { int r=i/13,k=i-r*13; inT[i] = temp[(long)(r0+r)*13+k]; }
    __syncthreads();
    for (int i = tid; i < 16*II; i += 256) { int r=i>>7,u=i&127; float o=bi1[u];
        for (int k=0;k<25;++k) o += inA[r*25+k]*Wi1[k*II+u];
        bufA[i]=relu_(o); }
    __syncthreads();
    for (int i = tid; i < 16*II; i += 256) { int r=i>>7,u=i&127; float o=bi2[u];
        for (int k=0;k<II;++k) o += bufA[r*II+k]*Wi2[k*II+u];
        bufB[i]=relu_(o); }
    __syncthreads();
    for (int i = tid; i < 16*64; i += 256) { int r=i>>6,u=i&63; float o=bi3[u];
        for (int k=0;k<II;++k) o += bufB[r*II+k]*Wi3[k*64+u];
        bufA[r*64+u]=relu_(o); }
    __syncthreads();
    for (int i = tid; i < 16*II; i += 256) { int r=i>>7,u=i&127; float o=bi4[u];
        for (int k=0;k<64;++k) o += bufA[r*64+k]*Wi4[k*II+u];
        infout[(long)(r0+r)*II+u]=relu_(o); }
    for (int i = tid; i < 16*64; i += 256) { int r=i>>6,u=i&63; float o=bt1[u];
        for (int k=0;k<13;++k) o += inT[r*13+k]*Wt1[k*64+u];
        bufB[r*64+u]=relu_(o); }
    __syncthreads();
    for (int i = tid; i < 16*II; i += 256) { int r=i>>7,u=i&127; float o=bt2[u];
        for (int k=0;k<64;++k) o += bufB[r*64+k]*Wt2[k*II+u];
        tpout[(long)(r0+r)*II+u]=relu_(o); }
}

// ---------------- li = relu(cat@Wcat+bcat); xg = li@Wih^T + bih + bhh -------
__global__ __launch_bounds__(256) void li_xg_kernel(
    const float* __restrict__ g_pre, const float* __restrict__ bgfc,
    const float* __restrict__ infb, const float* __restrict__ tpb,
    const float* __restrict__ Wcat, const float* __restrict__ bcat,
    const float* __restrict__ Wih, const float* __restrict__ bih,
    const float* __restrict__ bhh, float* __restrict__ xg)
{
    __shared__ float cat[16*384];
    __shared__ __align__(16) float li[16*II];
    const int r0 = blockIdx.x * 16, tid = threadIdx.x;

    for (int i = tid; i < 16*II; i += 256) {
        int r = i>>7, u = i&127;
        cat[r*384 + u]       = relu_(g_pre[(long)(r0+r)*II+u] + bgfc[u]);
        cat[r*384 + 128 + u] = infb[(long)(r0+r)*II+u];
        cat[r*384 + 256 + u] = tpb[(long)(r0+r)*II+u];
    }
    __syncthreads();
    {
        int u = tid & 127, rh = tid >> 7;
        float acc[8];
        #pragma unroll
        for (int x = 0; x < 8; ++x) acc[x] = bcat[u];
        for (int k = 0; k < 384; ++k) {
            float w = Wcat[k*II+u];
            #pragma unroll
            for (int x = 0; x < 8; ++x) acc[x] += cat[(rh*8+x)*384 + k] * w;
        }
        #pragma unroll
        for (int x = 0; x < 8; ++x) li[(rh*8+x)*II + u] = relu_(acc[x]);
    }
    __syncthreads();
    for (int jj = 0; jj < 4; ++jj) {
        int j = tid + jj*256;
        float bb = bih[j] + bhh[j];
        float acc[16];
        #pragma unroll
        for (int r = 0; r < 16; ++r) acc[r] = bb;
        for (int k4 = 0; k4 < 32; ++k4) {
            float4 wv = *(const float4*)&Wih[(long)j*II + k4*4];
            #pragma unroll
            for (int r = 0; r < 16; ++r) {
                float4 lv = *(const float4*)&li[r*II + k4*4];
                acc[r] += wv.x*lv.x + wv.y*lv.y + wv.z*lv.z + wv.w*lv.w;
            }
        }
        #pragma unroll
        for (int r = 0; r < 16; ++r) xg[(long)(r0+r)*1024 + j] = acc[r];
    }
}

// ---------------- pack Whh fp32 -> fp16 register/LDS layouts ----------------
// Thread u of the LSTM block owns rows R0=(u>>8)*512+(u&255), R1=R0+256.
// wreg_pack: [u(512)][r(2)][j(96)] h2   (k2 = j)          -> 98304 h2
// wlds_pack: [r(2)][c(8)][u(512)][q(4)] h2 (k2 = 96+4c+q) -> 32768 h2
__global__ __launch_bounds__(256) void pack_whh_kernel(
    const float* __restrict__ Whh, h2* __restrict__ wreg_pack,
    h2* __restrict__ wlds_pack)
{
    int i = blockIdx.x*256 + threadIdx.x;
    if (i < WREG_H2) {
        int u = i / (2*RJ2), rem = i % (2*RJ2), r = rem / RJ2, j = rem % RJ2;
        int row = ((u>>8)*2 + r)*256 + (u&255);
        h2 v; v[0] = (_Float16)Whh[(long)row*HH + 2*j];
        v[1] = (_Float16)Whh[(long)row*HH + 2*j + 1];
        wreg_pack[i] = v;
    } else {
        int L = i - WREG_H2;
        if (L < WLDS_H8*4) {
            int q = L & 3, u = (L >> 2) & 511, rc = L >> 11;
            int c = rc & 7, r = rc >> 3;
            int k2 = RJ2 + c*4 + q;
            int row = ((u>>8)*2 + r)*256 + (u&255);
            h2 v; v[0] = (_Float16)Whh[(long)row*HH + 2*k2];
            v[1] = (_Float16)Whh[(long)row*HH + 2*k2 + 1];
            wlds_pack[L] = v;
        }
    }
}

// ---------------- LSTM: one block/batch, 512 thr, reg+LDS resident Whh ------
// u<256: rows {v, 256+v} (gates i,f); u>=256: rows {512+v, 768+v} (g,o).
__global__ __launch_bounds__(512, 2) void lstm_kernel(
    const float* __restrict__ xg, const h2* __restrict__ wreg_pack,
    const h8* __restrict__ wlds_pack, const float* __restrict__ h0,
    const float* __restrict__ c0, float* __restrict__ hbuf)
{
    const int u = threadIdx.x;
    const int v = u & 255;
    const int b = blockIdx.x;
    const int R0 = (u >> 8)*512 + v;           // first owned row

    __shared__ __align__(16) _Float16 harr[2][HH];
    __shared__ __align__(16) h8 wlds[WLDS_H8];   // 128 KB
    __shared__ float2 gex[256];

    for (int i = u; i < WLDS_H8; i += 512) wlds[i] = wlds_pack[i];

    h8 wreg[2*RJ8];                              // 48 h8 = 192 VGPRs
    {
        const h8* wp = (const h8*)wreg_pack + (size_t)u * (2*RJ8);
        #pragma unroll
        for (int m = 0; m < 2*RJ8; ++m) wreg[m] = wp[m];
    }

    float c = 0.f;
    if (u < 256) c = c0[b*HH + v];
    if (u < 256) harr[0][v] = (_Float16)h0[b*HH + v];
    __syncthreads();

    const float* xgb = xg + (size_t)b*TT*1024;
    float h_last = 0.f;

    #pragma unroll 1
    for (int t = 0; t < TT; ++t) {
        const int cb = t & 1;
        float x0 = xgb[t*1024 + R0];
        float x1 = xgb[t*1024 + R0 + 256];

        const h8* hp = (const h8*)&harr[cb][0];
        float a00 = 0.f, a01 = 0.f, a10 = 0.f, a11 = 0.f;

        #pragma unroll
        for (int jj = 0; jj < RJ8; ++jj) {
            h8 hv = hp[jj];
            h2 hq0 = __builtin_shufflevector(hv, hv, 0, 1);
            h2 hq1 = __builtin_shufflevector(hv, hv, 2, 3);
            h2 hq2 = __builtin_shufflevector(hv, hv, 4, 5);
            h2 hq3 = __builtin_shufflevector(hv, hv, 6, 7);
            {
                h8 wv = wreg[jj];
                a00 = dot2_(__builtin_shufflevector(wv, wv, 0, 1), hq0, a00);
                a01 = dot2_(__builtin_shufflevector(wv, wv, 2, 3), hq1, a01);
                a00 = dot2_(__builtin_shufflevector(wv, wv, 4, 5), hq2, a00);
                a01 = dot2_(__builtin_shufflevector(wv, wv, 6, 7), hq3, a01);
            }
            {
                h8 wv = wreg[RJ8 + jj];
                a10 = dot2_(__builtin_shufflevector(wv, wv, 0, 1), hq0, a10);
                a11 = dot2_(__builtin_shufflevector(wv, wv, 2, 3), hq1, a11);
                a10 = dot2_(__builtin_shufflevector(wv, wv, 4, 5), hq2, a10);
                a11 = dot2_(__builtin_shufflevector(wv, wv, 6, 7), hq3, a11);
            }
        }
        #pragma unroll
        for (int cc = 0; cc < LC8; ++cc) {
            h8 hv = hp[RJ8 + cc];
            h2 hq0 = __builtin_shufflevector(hv, hv, 0, 1);
            h2 hq1 = __builtin_shufflevector(hv, hv, 2, 3);
            h2 hq2 = __builtin_shufflevector(hv, hv, 4, 5);
            h2 hq3 = __builtin_shufflevector(hv, hv, 6, 7);
            {
                h8 wv = wlds[cc*512 + u];
                a00 = dot2_(__builtin_shufflevector(wv, wv, 0, 1), hq0, a00);
                a01 = dot2_(__builtin_shufflevector(wv, wv, 2, 3), hq1, a01);
                a00 = dot2_(__builtin_shufflevector(wv, wv, 4, 5), hq2, a00);
                a01 = dot2_(__builtin_shufflevector(wv, wv, 6, 7), hq3, a01);
            }
            {
                h8 wv = wlds[(LC8 + cc)*512 + u];
                a10 = dot2_(__builtin_shufflevector(wv, wv, 0, 1), hq0, a10);
                a11 = dot2_(__builtin_shufflevector(wv, wv, 2, 3), hq1, a11);
                a10 = dot2_(__builtin_shufflevector(wv, wv, 4, 5), hq2, a10);
                a11 = dot2_(__builtin_shufflevector(wv, wv, 6, 7), hq3, a11);
            }
        }

        float g0 = a00 + a01 + x0;   // gate i (u<256) or g (u>=256)
        float g1 = a10 + a11 + x1;   // gate f (u<256) or o (u>=256)
        if (u >= 256) gex[v] = make_float2(g0, g1);
        __syncthreads();
        if (u < 256) {
            float2 gго = gex[v];
            c = sigmoid_(g1)*c + sigmoid_(g0)*tanhf(gго.x);
            float h = sigmoid_(gго.y)*tanhf(c);
            harr[cb^1][v] = (_Float16)h;
            h_last = h;
        }
        __syncthreads();
    }
    if (u < 256) hbuf[b*HH + v] = h_last;
}

// ---------------- final FC: out = relu(relu(h_T) @ Wfc + bfc) ---------------
__global__ __launch_bounds__(256) void final_fc_kernel(
    const float* __restrict__ hbuf, const float* __restrict__ Wfc,
    const float* __restrict__ bfc, float* __restrict__ out)
{
    int idx = blockIdx.x*256 + threadIdx.x;
    if (idx >= BB*N2) return;
    int b = idx / N2, j = idx - b*N2;
    const float* h = hbuf + b*HH;
    float o = bfc[j];
    for (int k = 0; k < HH; ++k) o += fmaxf(h[k], 0.f) * Wfc[(long)k*N2 + j];
    out[idx] = relu_(o);
}

extern "C" void kernel_launch(void* const* d_in, const int* in_sizes, int n_in,
                              void* d_out, int out_size, void* d_ws, size_t ws_size,
                              hipStream_t stream) {
    const float* nf     = (const float*)d_in[0];
    const int*   esrc   = (const int*)d_in[1];
    const int*   edst   = (const int*)d_in[2];
    const float* ew     = (const float*)d_in[3];
    const float* infect = (const float*)d_in[4];
    const float* temp   = (const float*)d_in[5];
    const float* h0     = (const float*)d_in[6];
    const float* c0     = (const float*)d_in[7];
    const float* Wg1    = (const float*)d_in[8];
    const float* bg1    = (const float*)d_in[9];
    const float* Wg2    = (const float*)d_in[10];
    const float* bg2    = (const float*)d_in[11];
    const float* Wgfc   = (const float*)d_in[12];
    const float* bgfc   = (const float*)d_in[13];
    const float* Wi1    = (const float*)d_in[14];
    const float* bi1    = (const float*)d_in[15];
    const float* Wi2    = (const float*)d_in[16];
    const float* bi2    = (const float*)d_in[17];
    const float* Wi3    = (const float*)d_in[18];
    const float* bi3    = (const float*)d_in[19];
    const float* Wi4    = (const float*)d_in[20];
    const float* bi4    = (const float*)d_in[21];
    const float* Wt1    = (const float*)d_in[22];
    const float* bt1    = (const float*)d_in[23];
    const float* Wt2    = (const float*)d_in[24];
    const float* bt2    = (const float*)d_in[25];
    const float* Wcat   = (const float*)d_in[26];
    const float* bcat   = (const float*)d_in[27];
    const float* Wih    = (const float*)d_in[28];
    const float* Whh    = (const float*)d_in[29];
    const float* bih    = (const float*)d_in[30];
    const float* bhh    = (const float*)d_in[31];
    const float* Wfc    = (const float*)d_in[32];
    const float* bfc    = (const float*)d_in[33];

    char* ws = (char*)d_ws;
    size_t off = 0;
    __hip_bfloat16* x2g = (__hip_bfloat16*)(ws + off); off += (size_t)BT*K2*2;
    float* g_pre = (float*)(ws + off); off += (size_t)BT*II*4;
    float* infb  = (float*)(ws + off); off += (size_t)BT*II*4;
    float* tpb   = (float*)(ws + off); off += (size_t)BT*II*4;
    float* xg    = (float*)(ws + off); off += (size_t)BT*1024*4;
    float* hbuf  = (float*)(ws + off); off += (size_t)BB*HH*4;
    h2* wreg_pack = (h2*)(ws + off); off += (size_t)WREG_H2*4;
    h8* wlds_pack = (h8*)(ws + off); off += (size_t)WLDS_H8*16;

    hipMemsetAsync(g_pre, 0, (size_t)BT*II*4, stream);

    pack_whh_kernel<<<512, 256, 0, stream>>>(Whh, (h2*)wreg_pack, (h2*)wlds_pack);
    gcn_kernel<<<BT, 256, 0, stream>>>(nf, esrc, edst, ew, Wg1, bg1, Wg2, bg2, x2g);
    branches_kernel<<<BT/16, 256, 0, stream>>>(infect, temp, Wi1, bi1, Wi2, bi2,
                                               Wi3, bi3, Wi4, bi4, Wt1, bt1, Wt2, bt2,
                                               infb, tpb);
    gemm_kernel<<<dim3(BT/GMT, K2/GKC), 256, 0, stream>>>(x2g, Wgfc, g_pre);
    li_xg_kernel<<<BT/16, 256, 0, stream>>>(g_pre, bgfc, infb, tpb, Wcat, bcat,
                                            Wih, bih, bhh, xg);
    lstm_kernel<<<BB, 512, 0, stream>>>(xg, wreg_pack, wlds_pack, h0, c0, hbuf);
    final_fc_kernel<<<(BB*N2 + 255)/256, 256, 0, stream>>>(hbuf, Wfc, bfc, (float*)d_out);
}